// Round 18
// baseline (404.017 us; speedup 1.0000x reference)
//
#include <hip/hip_runtime.h>
#include <hip/hip_bf16.h>

#define H_ 16
#define B_ 8
#define S_ 1024
#define D_ 1024
#define E_ 64
#define HB_ 128
#define LN_EPS 1e-5f
#define LOG2E 1.4426950408889634f

typedef unsigned short u16;
typedef __bf16 bf16x8 __attribute__((ext_vector_type(8)));
typedef u16 u16x8 __attribute__((ext_vector_type(8)));
typedef u16 u16x4 __attribute__((ext_vector_type(4)));
typedef float f32x4 __attribute__((ext_vector_type(4)));
typedef unsigned u32x2 __attribute__((ext_vector_type(2)));

#define MFMA16(a, b, c) __builtin_amdgcn_mfma_f32_16x16x32_bf16( \
    __builtin_bit_cast(bf16x8, (a)), __builtin_bit_cast(bf16x8, (b)), (c), 0, 0, 0)

// async global->LDS, 16B per lane; LDS dest must be wave-uniform base (+lane*16 by HW)
#define GLL16(gp, lp) __builtin_amdgcn_global_load_lds( \
    (const __attribute__((address_space(1))) void*)(gp), \
    (__attribute__((address_space(3))) void*)(lp), 16, 0, 0)

// packed f32x2 -> bf16x2 (RNE), 1 instr for 2 values
__device__ __forceinline__ unsigned cvt_pk_bf16(float lo, float hi) {
  unsigned r;
  asm("v_cvt_pk_bf16_f32 %0, %1, %2" : "=v"(r) : "v"(lo), "v"(hi));
  return r;
}
__device__ __forceinline__ u16x4 pk4(f32x4 v) {
  union { unsigned u[2]; u16x4 s; } r;
  r.u[0] = cvt_pk_bf16(v[0], v[1]);
  r.u[1] = cvt_pk_bf16(v[2], v[3]);
  return r.s;
}
// raw v_exp_f32: computes 2^x
__device__ __forceinline__ float exp2_hw(float x) {
  float r;
  asm("v_exp_f32 %0, %1" : "=v"(r) : "v"(x));
  return r;
}
__device__ __forceinline__ float bfhi(unsigned u) {   // high bf16 of dword -> f32
  return __builtin_bit_cast(float, u & 0xFFFF0000u);
}
__device__ __forceinline__ float bflo(unsigned u) {   // low bf16 of dword -> f32
  return __builtin_bit_cast(float, u << 16);
}

// ---- prep: weight transposes (bid<1024) + X f32->bf16 convert (bid>=1024) ----
// Wq folded scale = log2(e)/sqrt(1024): scores come out in exp2 domain.
__global__ __launch_bounds__(256) void k_prep(
    const float* __restrict__ Wq, const float* __restrict__ Wk,
    const float* __restrict__ Wv, const float* __restrict__ Wp,
    u16* __restrict__ Wt,
    const float* __restrict__ Xq, const float* __restrict__ Xk,
    const float* __restrict__ Xv, u16* __restrict__ Xdst) {
  const int bid = blockIdx.x;
  if (bid >= 1024) {
    const int b2 = bid - 1024;
    const int t = b2 >> 12;                       // 0,1,2
    const float* X = t == 0 ? Xq : t == 1 ? Xk : Xv;
    u16* Y = Xdst + (size_t)t * (8 << 20);
    int i = ((b2 & 4095) * 256 + threadIdx.x) * 8;
    f32x4 a = *(const f32x4*)(X + i);
    f32x4 b = *(const f32x4*)(X + i + 4);
    union { unsigned u[4]; u16x8 s; } v;
    v.u[0] = cvt_pk_bf16(a[0], a[1]);
    v.u[1] = cvt_pk_bf16(a[2], a[3]);
    v.u[2] = cvt_pk_bf16(b[0], b[1]);
    v.u[3] = cvt_pk_bf16(b[2], b[3]);
    *(u16x8*)(Y + i) = v.s;
    return;
  }
  __shared__ float tile[64][65];
  const int which = bid >> 8, r = bid & 255;
  const float* src;
  int R, C, rt, ct;
  float scale = 1.0f;
  size_t soff, doff;
  if (which < 3) {
    src = which == 0 ? Wq : which == 1 ? Wk : Wv;
    if (which == 0) scale = LOG2E / 32.0f;
    int slice = r & 15, rtile = r >> 4;
    R = 1024; C = 64; rt = rtile * 64; ct = 0;
    soff = (size_t)slice * 65536;
    doff = (size_t)which * (1 << 20) + (size_t)slice * 65536;
  } else {
    src = Wp;
    R = 1024; C = 1024; rt = (r & 15) * 64; ct = (r >> 4) * 64;
    soff = 0; doff = (size_t)3 * (1 << 20);
  }
  const float* I = src + soff;
  u16* O = Wt + doff;
  const int t = threadIdx.x;
  const int c4 = (t & 15) * 4;
  #pragma unroll
  for (int i = 0; i < 4; i++) {
    int rr = i * 16 + (t >> 4);
    f32x4 v = *(const f32x4*)&I[(size_t)(rt + rr) * C + ct + c4];
    tile[rr][c4 + 0] = v[0]; tile[rr][c4 + 1] = v[1];
    tile[rr][c4 + 2] = v[2]; tile[rr][c4 + 3] = v[3];
  }
  __syncthreads();
  #pragma unroll
  for (int i = 0; i < 4; i++) {
    int oc = i * 16 + (t >> 4);
    f32x4 tv;
    #pragma unroll
    for (int rr = 0; rr < 4; rr++) tv[rr] = tile[c4 + rr][oc] * scale;
    *(u16x4*)&O[(size_t)(ct + oc) * R + rt + c4] = pk4(tv);
  }
}

// ---- staging for BK=64: tile 128x64 u16 = 16KB per matrix, 16 GLL16 total ----
#define STAGE64() do { \
    _Pragma("unroll") \
    for (int i = 0; i < 4; i++) { \
      GLL16(Ag + (size_t)i * 8 * 1024 + kt, AsB0 + i * 512); \
      GLL16(Bg + (size_t)i * 8 * 1024 + kt, BsB0 + i * 512); \
    } \
  } while (0)

#define READ_FRAGS64(kk) do { \
    _Pragma("unroll") \
    for (int mi = 0; mi < 4; mi++) \
      af[mi] = *(const u16x8*)&As[(wr * 64 + mi * 16 + lr) * 64 + (kk) * 32 + lg * 8]; \
    _Pragma("unroll") \
    for (int ni = 0; ni < 4; ni++) \
      bf[ni] = *(const u16x8*)&Bs[(wc * 64 + ni * 16 + lr) * 64 + (kk) * 32 + lg * 8]; \
  } while (0)

// ---- m97-structure GEMM: 128x128 tile, BK=64, 4 waves, global_load_lds staging.
// __launch_bounds__(256,4): VGPR<=128 -> 4 wg/CU (LDS 32KB allows 5). BK=64 halves
// the per-K-loop barrier/vmcnt-drain count vs BK=32 (the modeled ~20% stall).
// merged QKV, grid (64,24). by 0..7 Q, 8..15 K (swapped mfma), 16..23 V (normal).
template<int MODE>
__global__ __launch_bounds__(256, 4) void k_gemm(
    const u16* __restrict__ X0, const u16* __restrict__ Ball,
    u16* __restrict__ O0, u16* __restrict__ O1, u16* __restrict__ O2) {
  const int bid = blockIdx.x + (blockIdx.y << 6);
  const int bx  = ((bid & 7) << 3) + ((bid >> 3) & 7);   // m-tile, XCD-local slice
  const int by  = bid >> 6;                               // n-tile
  const int l  = threadIdx.x & 63;
  const int w  = threadIdx.x >> 6;
  const int lr = l & 15, lg = l >> 4;
  const int wr = w >> 1, wc = w & 1;
  const int m0 = bx * 128;

  const u16* A = X0 + (size_t)(by >> 3) * (8 << 20);

  __shared__ __align__(16) u16 As[128 * 64];
  __shared__ __align__(16) u16 Bs[128 * 64];

  // staging: global instr g = w*4+i covers rows [w*32+i*8, +8); lane l -> row +(l>>3), col (l&7)*8
  const int srow = l >> 3;
  const int scol = (l & 7) * 8;
  const u16* Ag = A    + (size_t)(m0 + w * 32 + srow) * 1024 + scol;
  const u16* Bg = Ball + (size_t)(by * 128 + w * 32 + srow) * 1024 + scol;
  u16* AsB0 = As + w * 2048;          // uniform per wave (32 rows x 64 cols)
  u16* BsB0 = Bs + w * 2048;

  f32x4 acc[4][4] = {};
  u16x8 af[4], bf[4];

  if (by < 16) {
    for (int kt = 0; kt < 1024; kt += 64) {
      STAGE64();
      __syncthreads();
      #pragma unroll
      for (int kk = 0; kk < 2; kk++) {
        READ_FRAGS64(kk);
        #pragma unroll
        for (int mi = 0; mi < 4; mi++)
          #pragma unroll
          for (int ni = 0; ni < 4; ni++)
            acc[mi][ni] = MFMA16(bf[ni], af[mi], acc[mi][ni]);   // swapped
      }
      __syncthreads();
    }
  } else {
    for (int kt = 0; kt < 1024; kt += 64) {
      STAGE64();
      __syncthreads();
      #pragma unroll
      for (int kk = 0; kk < 2; kk++) {
        READ_FRAGS64(kk);
        #pragma unroll
        for (int mi = 0; mi < 4; mi++)
          #pragma unroll
          for (int ni = 0; ni < 4; ni++)
            acc[mi][ni] = MFMA16(af[mi], bf[ni], acc[mi][ni]);   // normal (V)
      }
      __syncthreads();
    }
  }

  if (by < 16) {
    u16* Out = (by >= 8) ? O1 : O0;
    const int h = (by & 7) * 2 + wc;
    #pragma unroll
    for (int mi = 0; mi < 4; mi++) {
      int s = m0 + wr * 64 + mi * 16 + lr;
      int bb = s >> 10, ss = s & 1023;
      #pragma unroll
      for (int ni = 0; ni < 4; ni++)
        *(u16x4*)&Out[((size_t)(h * 8 + bb) * 1024 + ss) * 64 + ni * 16 + lg * 4] =
            pk4(acc[mi][ni]);
    }
  } else {
    const int byv = by - 16;
    const int h = byv * 2 + wc;
    #pragma unroll
    for (int mi = 0; mi < 4; mi++) {
      int s = m0 + wr * 64 + mi * 16 + lg * 4;
      int bb = s >> 10, ss = s & 1023;
      #pragma unroll
      for (int ni = 0; ni < 4; ni++)
        *(u16x4*)&O2[((size_t)(h * 8 + bb) * 64 + ni * 16 + lr) * 1024 + ss] =
            pk4(acc[mi][ni]);
    }
  }
}

// ---- proj GEMM: BM=128 x BN=64, BK=32 -> grid 1024 wgs. Swapped mfma ->
// D[row=n][col=m]; epilogue fuses +bias+residual, f32x4 stores into P.
__global__ __launch_bounds__(256, 4) void k_proj(const u16* __restrict__ AO,
    const u16* __restrict__ Wpt, const float* __restrict__ bp,
    const float* __restrict__ query, float* __restrict__ Pf) {
  const int bid = blockIdx.x;
  const int bx  = ((bid & 7) << 3) + ((bid >> 3) & 7);   // 0..63, XCD-local slice
  const int by  = bid >> 6;                               // 0..15
  const int l  = threadIdx.x & 63;
  const int w  = threadIdx.x >> 6;
  const int lr = l & 15, lg = l >> 4;
  const int wr = w >> 1, wc = w & 1;
  const int m0 = bx * 128, n0 = by * 64;

  __shared__ __align__(16) u16 As[128 * 32];   // 8 KB
  __shared__ __align__(16) u16 Bs[64 * 32];    // 4 KB

  const int srow = w * 16 + (l >> 2);          // < 64
  const int scol = (l & 3) * 8;
  const u16* Ag = AO  + (size_t)(m0 + srow) * 1024 + scol;
  const u16* Bg = Wpt + (size_t)(n0 + srow) * 1024 + scol;
  u16* AsB0 = As + w * 512;
  u16* BsB0 = Bs + w * 512;

  f32x4 acc[4][2] = {};

  for (int kt = 0; kt < 1024; kt += 32) {
    GLL16(Ag + kt,             AsB0);
    GLL16(Ag + 64 * 1024 + kt, AsB0 + 2048);
    GLL16(Bg + kt,             BsB0);
    __syncthreads();

    u16x8 af[4], bf[2];
    #pragma unroll
    for (int mi = 0; mi < 4; mi++)
      af[mi] = *(const u16x8*)&As[(wr * 64 + mi * 16 + lr) * 32 + lg * 8];
    #pragma unroll
    for (int ni = 0; ni < 2; ni++)
      bf[ni] = *(const u16x8*)&Bs[(wc * 32 + ni * 16 + lr) * 32 + lg * 8];

    #pragma unroll
    for (int mi = 0; mi < 4; mi++)
      #pragma unroll
      for (int ni = 0; ni < 2; ni++)
        acc[mi][ni] = MFMA16(bf[ni], af[mi], acc[mi][ni]);  // D[row=n][col=m]
    __syncthreads();
  }

  #pragma unroll
  for (int mi = 0; mi < 4; mi++) {
    int m = m0 + wr * 64 + mi * 16 + lr;
    #pragma unroll
    for (int ni = 0; ni < 2; ni++) {
      int n = n0 + wc * 32 + ni * 16 + lg * 4;
      f32x4 b4 = *(const f32x4*)(bp + n);
      f32x4 q4 = *(const f32x4*)(query + (size_t)m * 1024 + n);
      f32x4 o = acc[mi][ni] + b4 + q4;
      *(f32x4*)(Pf + (size_t)m * 1024 + n) = o;
    }
  }
}

// ---- attention (R12-exact): wg = (hb, 16 q rows); ONE barrier. Post-barrier:
// issue slice0-tail + slice1 V loads -> 16 row-contiguous 1KB NT stores ->
// PV slice-by-slice with single accumulator + inter-slice rescale.
__global__ __launch_bounds__(256, 4) void k_attn(const u16* __restrict__ Qb,
    const u16* __restrict__ Kb, const u16* __restrict__ Vtb,
    float* __restrict__ attn_out, u16* __restrict__ AO) {
  const int bid = blockIdx.x;
  const int xcd = bid & 7, within = bid >> 3;
  const int qt = within & 63;
  const int hb = xcd * 16 + (within >> 6);
  const int w  = threadIdx.x >> 6;
  const int l  = threadIdx.x & 63;
  const int lr = l & 15, lg = l >> 4;
  const int q0 = qt * 16;

  __shared__ __align__(16) u16 pbuf[16 * 1024];   // 32 KB, swizzled; raw exp2(s - wmax_w)
  __shared__ float wmaxs[4][16];
  __shared__ float wsums[4][16];

  // --- QK^T swapped: mfma(K,Q) -> thread holds S[q=lr][k = w*256 + j*16 + lg*4 + r]
  const u16* Qp = Qb + ((size_t)hb * 1024 + q0 + lr) * 64 + lg * 8;
  const u16* Kp = Kb + ((size_t)hb * 1024 + w * 256 + lr) * 64 + lg * 8;
  u16x8 q_lo = *(const u16x8*)Qp;
  u16x8 q_hi = *(const u16x8*)(Qp + 32);

  f32x4 sacc[16] = {};
  __builtin_amdgcn_s_setprio(1);
  #pragma unroll
  for (int j = 0; j < 16; j++) {
    u16x8 k0 = *(const u16x8*)(Kp + (size_t)j * 16 * 64);
    u16x8 k1 = *(const u16x8*)(Kp + (size_t)j * 16 * 64 + 32);
    sacc[j] = MFMA16(k0, q_lo, sacc[j]);
    sacc[j] = MFMA16(k1, q_hi, sacc[j]);
  }
  __builtin_amdgcn_s_setprio(0);

  // --- wave-local row max over this wave's 256-col slice ---
  float mx = sacc[0][0];
  #pragma unroll
  for (int j = 0; j < 16; j++)
    #pragma unroll
    for (int r = 0; r < 4; r++) mx = fmaxf(mx, sacc[j][r]);
  mx = fmaxf(mx, __shfl_xor(mx, 16));
  mx = fmaxf(mx, __shfl_xor(mx, 32));

  // --- exp2(s - wmax) + wave-local sum (v_exp_f32 is 2^x; scores pre-scaled) ---
  float sum = 0.f;
  #pragma unroll
  for (int j = 0; j < 16; j++)
    #pragma unroll
    for (int r = 0; r < 4; r++) {
      float p = exp2_hw(sacc[j][r] - mx);
      sacc[j][r] = p;
      sum += p;
    }
  sum += __shfl_xor(sum, 16);
  sum += __shfl_xor(sum, 32);

  // --- prefetch V slice0 kk=0..3 (latency hides under LDS writes + barrier) ---
  const u16* Vp = Vtb + ((size_t)hb * 64 + w * 16 + lr) * 1024 + lg * 8;
  u16x8 vp0 = *(const u16x8*)(Vp + 0);
  u16x8 vp1 = *(const u16x8*)(Vp + 32);
  u16x8 vp2 = *(const u16x8*)(Vp + 64);
  u16x8 vp3 = *(const u16x8*)(Vp + 96);

  // --- raw-exp2 P -> swizzled pbuf (bf16); sacc DIES here ---
  #pragma unroll
  for (int j = 0; j < 16; j++) {
    int k0 = w * 256 + j * 16 + lg * 4;
    int byte = (lr * 2048 + k0 * 2) ^ ((lr & 7) << 4);
    *(u16x4*)((char*)pbuf + byte) = pk4(sacc[j]);
  }
  if (l < 16) { wmaxs[w][lr] = mx; wsums[w][lr] = sum; }

  __syncthreads();   // the only barrier: drains LDS writes only (no global stores yet)

  // --- combine for PV (row q = lr): rescale ratios + final coef ---
  float m0v = wmaxs[0][lr], m1v = wmaxs[1][lr], m2v = wmaxs[2][lr], m3v = wmaxs[3][lr];
  float gmax = fmaxf(fmaxf(m0v, m1v), fmaxf(m2v, m3v));
  float gsum = wsums[0][lr] * exp2_hw(m0v - gmax) + wsums[1][lr] * exp2_hw(m1v - gmax)
             + wsums[2][lr] * exp2_hw(m2v - gmax) + wsums[3][lr] * exp2_hw(m3v - gmax);
  float r01 = exp2_hw(m0v - m1v);
  float r12 = exp2_hw(m1v - m2v);
  float r23 = exp2_hw(m2v - m3v);
  float c3  = exp2_hw(m3v - gmax) / gsum;

  // --- issue slice0 tail + slice1 V loads BEFORE any store hits the queue ---
  u16x8 vp4 = *(const u16x8*)(Vp + 128);
  u16x8 vp5 = *(const u16x8*)(Vp + 160);
  u16x8 vp6 = *(const u16x8*)(Vp + 192);
  u16x8 vp7 = *(const u16x8*)(Vp + 224);
  u16x8 vq0 = *(const u16x8*)(Vp + 256);
  u16x8 vq1 = *(const u16x8*)(Vp + 288);
  u16x8 vq2 = *(const u16x8*)(Vp + 320);
  u16x8 vq3 = *(const u16x8*)(Vp + 352);
  u16x8 vq4 = *(const u16x8*)(Vp + 384);
  u16x8 vq5 = *(const u16x8*)(Vp + 416);
  u16x8 vq6 = *(const u16x8*)(Vp + 448);
  u16x8 vq7 = *(const u16x8*)(Vp + 480);

  // --- attn f32 out: wave w owns rows [w*4, w*4+4); per (row, chunk) scale is
  //     lane-uniform -> one contiguous 1KB NT store per instruction ---
  #pragma unroll
  for (int rr = 0; rr < 4; rr++) {
    const int row = w * 4 + rr;
    float M0 = wmaxs[0][row], M1 = wmaxs[1][row], M2 = wmaxs[2][row], M3 = wmaxs[3][row];
    float GM = fmaxf(fmaxf(M0, M1), fmaxf(M2, M3));
    float E0 = exp2_hw(M0 - GM), E1 = exp2_hw(M1 - GM);
    float E2 = exp2_hw(M2 - GM), E3 = exp2_hw(M3 - GM);
    float IV = 1.0f / (wsums[0][row] * E0 + wsums[1][row] * E1 +
                       wsums[2][row] * E2 + wsums[3][row] * E3);
    float cs0 = E0 * IV, cs1 = E1 * IV, cs2 = E2 * IV, cs3 = E3 * IV;
    float* Ap = attn_out + ((size_t)hb * 1024 + q0 + row) * 1024;
    #pragma unroll
    for (int c = 0; c < 4; c++) {
      float sc = c == 0 ? cs0 : c == 1 ? cs1 : c == 2 ? cs2 : cs3;
      int byte = (row * 2048 + (c * 256 + l * 4) * 2) ^ ((row & 7) << 4);
      u32x2 d = *(u32x2*)((char*)pbuf + byte);
      f32x4 v;
      v[0] = bflo(d[0]) * sc;
      v[1] = bfhi(d[0]) * sc;
      v[2] = bflo(d[1]) * sc;
      v[3] = bfhi(d[1]) * sc;
      __builtin_nontemporal_store(v, (f32x4*)(Ap + c * 256 + l * 4));
    }
  }

  // --- PV: mfma(V, P) -> D[row=e][col=q=lr]; single acc + inter-slice rescale ---
  f32x4 o = {};
  __builtin_amdgcn_s_setprio(1);
  #define PBUF_P(i, kk) (*(u16x8*)((char*)pbuf + \
      ((lr * 2048 + ((i) * 256 + (kk) * 32 + lg * 8) * 2) ^ ((lr & 7) << 4))))
  // slice 0 (registers loaded pre-barrier / pre-store)
  o = MFMA16(vp0, PBUF_P(0, 0), o);
  o = MFMA16(vp1, PBUF_P(0, 1), o);
  o = MFMA16(vp2, PBUF_P(0, 2), o);
  o = MFMA16(vp3, PBUF_P(0, 3), o);
  o = MFMA16(vp4, PBUF_P(0, 4), o);
  o = MFMA16(vp5, PBUF_P(0, 5), o);
  o = MFMA16(vp6, PBUF_P(0, 6), o);
  o = MFMA16(vp7, PBUF_P(0, 7), o);
  // issue slice2 loads (reuse vp regs; store queue partially drained by now)
  vp0 = *(const u16x8*)(Vp + 512);
  vp1 = *(const u16x8*)(Vp + 544);
  vp2 = *(const u16x8*)(Vp + 576);
  vp3 = *(const u16x8*)(Vp + 608);
  vp4 = *(const u16x8*)(Vp + 640);
  vp5 = *(const u16x8*)(Vp + 672);
  vp6 = *(const u16x8*)(Vp + 704);
  vp7 = *(const u16x8*)(Vp + 736);
  o *= r01;
  // slice 1 (loaded before stores)
  o = MFMA16(vq0, PBUF_P(1, 0), o);
  o = MFMA16(vq1, PBUF_P(1, 1), o);
  o = MFMA16(vq2, PBUF_P(1, 2), o);
  o = MFMA16(vq3, PBUF_P(1, 3), o);
  o = MFMA16(vq4, PBUF_P(1, 4), o);
  o = MFMA16(vq5, PBUF_P(1, 5), o);
  o = MFMA16(vq6, PBUF_P(1, 6), o);
  o = MFMA16(vq7, PBUF_P(1, 7), o);
  // issue slice3 loads
  vq0 = *(const u16x8*)(Vp + 768);
  vq1 = *(const u16x8*)(Vp + 800);
  vq2 = *(const u16x8*)(Vp + 832);
  vq3 = *(const u16x8*)(Vp + 864);
  vq4 = *(const u16x8*)(Vp + 896);
  vq5 = *(const u16x8*)(Vp + 928);
  vq6 = *(const u16x8*)(Vp + 960);
  vq7 = *(const u16x8*)(Vp + 992);
  o *= r12;
  // slice 2
  o = MFMA16(vp0, PBUF_P(2, 0), o);
  o = MFMA16(vp1, PBUF_P(2, 1), o);
  o = MFMA16(vp2, PBUF_P(2, 2), o);
  o = MFMA16(vp3, PBUF_P(2, 3), o);
  o = MFMA16(vp4, PBUF_P(2, 4), o);
  o = MFMA16(vp5, PBUF_P(2, 5), o);
  o = MFMA16(vp6, PBUF_P(2, 6), o);
  o = MFMA16(vp7, PBUF_P(2, 7), o);
  o *= r23;
  // slice 3
  o = MFMA16(vq0, PBUF_P(3, 0), o);
  o = MFMA16(vq1, PBUF_P(3, 1), o);
  o = MFMA16(vq2, PBUF_P(3, 2), o);
  o = MFMA16(vq3, PBUF_P(3, 3), o);
  o = MFMA16(vq4, PBUF_P(3, 4), o);
  o = MFMA16(vq5, PBUF_P(3, 5), o);
  o = MFMA16(vq6, PBUF_P(3, 6), o);
  o = MFMA16(vq7, PBUF_P(3, 7), o);
  __builtin_amdgcn_s_setprio(0);
  #undef PBUF_P

  // --- AO store: q = lr, e = w*16 + lg*4 + r -> one u16x4 ---
  const int bb = hb & 7, hh = hb >> 3;
  f32x4 oc = o * c3;
  *(u16x4*)&AO[((size_t)bb * 1024 + q0 + lr) * 1024 + hh * 64 + w * 16 + lg * 4] = pk4(oc);
}

// ---- standalone LayerNorm over P rows (bias+residual already in P) ----
__global__ __launch_bounds__(256) void k_ln(const float* __restrict__ P,
    const float* __restrict__ gamma, const float* __restrict__ beta,
    float* __restrict__ y) {
  const int row = blockIdx.x * 4 + (threadIdx.x >> 6);
  const int l = threadIdx.x & 63;
  const float* p = P + (size_t)row * 1024 + l * 4;
  f32x4 v[4];
  float s = 0.f, s2 = 0.f;
  #pragma unroll
  for (int i = 0; i < 4; i++) {
    v[i] = *(const f32x4*)(p + i * 256);
    #pragma unroll
    for (int r = 0; r < 4; r++) { s += v[i][r]; s2 += v[i][r] * v[i][r]; }
  }
  #pragma unroll
  for (int off = 1; off < 64; off <<= 1) {
    s += __shfl_xor(s, off);
    s2 += __shfl_xor(s2, off);
  }
  float mu = s * (1.0f / 1024.0f);
  float var = s2 * (1.0f / 1024.0f) - mu * mu;
  float rstd = rsqrtf(var + LN_EPS);
  float* yp = y + (size_t)row * 1024 + l * 4;
  #pragma unroll
  for (int i = 0; i < 4; i++) {
    f32x4 g = *(const f32x4*)(gamma + l * 4 + i * 256);
    f32x4 b = *(const f32x4*)(beta + l * 4 + i * 256);
    f32x4 o;
    #pragma unroll
    for (int r = 0; r < 4; r++) o[r] = (v[i][r] - mu) * rstd * g[r] + b[r];
    __builtin_nontemporal_store(o, (f32x4*)(yp + i * 256));
  }
}

extern "C" void kernel_launch(void* const* d_in, const int* in_sizes, int n_in,
                              void* d_out, int out_size, void* d_ws, size_t ws_size,
                              hipStream_t stream) {
  const float* query  = (const float*)d_in[0];
  const float* keys   = (const float*)d_in[1];
  const float* values = (const float*)d_in[2];
  const float* Wq     = (const float*)d_in[3];
  const float* Wk     = (const float*)d_in[4];
  const float* Wv     = (const float*)d_in[5];
  const float* Wp     = (const float*)d_in[6];
  const float* bp     = (const float*)d_in[7];
  const float* gamma  = (const float*)d_in[8];
  const float* beta   = (const float*)d_in[9];

  float* y        = (float*)d_out;                         // [8,1024,1024]
  float* attn_out = (float*)d_out + (size_t)B_ * S_ * D_;  // [128,1024,1024]

  u16* ws  = (u16*)d_ws;
  u16* Wqt = ws;                   // weights: Wq|Wk|Wv|Wp transposed, 4M u16
  u16* Wpt = Wqt + (3 << 20);
  u16* Xqb = Wqt + (4 << 20);      // Xq|Xk|Xv bf16, 24M u16
  u16* Qb  = Xqb + (24 << 20);     // 8M each
  u16* Kb  = Qb + (8 << 20);
  u16* Vtb = Kb + (8 << 20);
  u16* AO  = Vtb + (8 << 20);      // 8M
  float* P = (float*)Xqb;          // proj+residual f32, overlays Xqb/Xkb (dead by then)

  k_prep<<<13312, 256, 0, stream>>>(Wq, Wk, Wv, Wp, Wqt, query, keys, values, Xqb);

  // merged QKV GEMM: by 0..7 Q, 8..15 K, 16..23 V
  k_gemm<0><<<dim3(64, 24), 256, 0, stream>>>(Xqb, Wqt, Qb, Kb, Vtb);

  k_attn<<<8192, 256, 0, stream>>>(Qb, Kb, Vtb, attn_out, AO);

  k_proj<<<1024, 256, 0, stream>>>(AO, Wpt, bp, query, P);
  k_ln<<<2048, 256, 0, stream>>>(P, gamma, beta, y);
}

// Round 19
// 381.746 us; speedup vs baseline: 1.0583x; 1.0583x over previous
//
#include <hip/hip_runtime.h>
#include <hip/hip_bf16.h>

#define H_ 16
#define B_ 8
#define S_ 1024
#define D_ 1024
#define E_ 64
#define HB_ 128
#define LN_EPS 1e-5f
#define LOG2E 1.4426950408889634f

typedef unsigned short u16;
typedef __bf16 bf16x8 __attribute__((ext_vector_type(8)));
typedef u16 u16x8 __attribute__((ext_vector_type(8)));
typedef u16 u16x4 __attribute__((ext_vector_type(4)));
typedef float f32x4 __attribute__((ext_vector_type(4)));
typedef unsigned u32x2 __attribute__((ext_vector_type(2)));
typedef unsigned u32x4 __attribute__((ext_vector_type(4)));

#define MFMA16(a, b, c) __builtin_amdgcn_mfma_f32_16x16x32_bf16( \
    __builtin_bit_cast(bf16x8, (a)), __builtin_bit_cast(bf16x8, (b)), (c), 0, 0, 0)

// async global->LDS, 16B per lane; LDS dest must be wave-uniform base (+lane*16 by HW)
#define GLL16(gp, lp) __builtin_amdgcn_global_load_lds( \
    (const __attribute__((address_space(1))) void*)(gp), \
    (__attribute__((address_space(3))) void*)(lp), 16, 0, 0)

// packed f32x2 -> bf16x2 (RNE), 1 instr for 2 values
__device__ __forceinline__ unsigned cvt_pk_bf16(float lo, float hi) {
  unsigned r;
  asm("v_cvt_pk_bf16_f32 %0, %1, %2" : "=v"(r) : "v"(lo), "v"(hi));
  return r;
}
__device__ __forceinline__ u16x4 pk4(f32x4 v) {
  union { unsigned u[2]; u16x4 s; } r;
  r.u[0] = cvt_pk_bf16(v[0], v[1]);
  r.u[1] = cvt_pk_bf16(v[2], v[3]);
  return r.s;
}
// raw v_exp_f32: computes 2^x
__device__ __forceinline__ float exp2_hw(float x) {
  float r;
  asm("v_exp_f32 %0, %1" : "=v"(r) : "v"(x));
  return r;
}
__device__ __forceinline__ float bfhi(unsigned u) {   // high bf16 of dword -> f32
  return __builtin_bit_cast(float, u & 0xFFFF0000u);
}
__device__ __forceinline__ float bflo(unsigned u) {   // low bf16 of dword -> f32
  return __builtin_bit_cast(float, u << 16);
}

// ---- prep: weight transposes (bid<1024) + X f32->bf16 convert (bid>=1024) ----
// Wq folded scale = log2(e)/sqrt(1024): scores come out in exp2 domain.
__global__ __launch_bounds__(256) void k_prep(
    const float* __restrict__ Wq, const float* __restrict__ Wk,
    const float* __restrict__ Wv, const float* __restrict__ Wp,
    u16* __restrict__ Wt,
    const float* __restrict__ Xq, const float* __restrict__ Xk,
    const float* __restrict__ Xv, u16* __restrict__ Xdst) {
  const int bid = blockIdx.x;
  if (bid >= 1024) {
    const int b2 = bid - 1024;
    const int t = b2 >> 12;                       // 0,1,2
    const float* X = t == 0 ? Xq : t == 1 ? Xk : Xv;
    u16* Y = Xdst + (size_t)t * (8 << 20);
    int i = ((b2 & 4095) * 256 + threadIdx.x) * 8;
    f32x4 a = *(const f32x4*)(X + i);
    f32x4 b = *(const f32x4*)(X + i + 4);
    union { unsigned u[4]; u16x8 s; } v;
    v.u[0] = cvt_pk_bf16(a[0], a[1]);
    v.u[1] = cvt_pk_bf16(a[2], a[3]);
    v.u[2] = cvt_pk_bf16(b[0], b[1]);
    v.u[3] = cvt_pk_bf16(b[2], b[3]);
    *(u16x8*)(Y + i) = v.s;
    return;
  }
  __shared__ float tile[64][65];
  const int which = bid >> 8, r = bid & 255;
  const float* src;
  int R, C, rt, ct;
  float scale = 1.0f;
  size_t soff, doff;
  if (which < 3) {
    src = which == 0 ? Wq : which == 1 ? Wk : Wv;
    if (which == 0) scale = LOG2E / 32.0f;
    int slice = r & 15, rtile = r >> 4;
    R = 1024; C = 64; rt = rtile * 64; ct = 0;
    soff = (size_t)slice * 65536;
    doff = (size_t)which * (1 << 20) + (size_t)slice * 65536;
  } else {
    src = Wp;
    R = 1024; C = 1024; rt = (r & 15) * 64; ct = (r >> 4) * 64;
    soff = 0; doff = (size_t)3 * (1 << 20);
  }
  const float* I = src + soff;
  u16* O = Wt + doff;
  const int t = threadIdx.x;
  const int c4 = (t & 15) * 4;
  #pragma unroll
  for (int i = 0; i < 4; i++) {
    int rr = i * 16 + (t >> 4);
    f32x4 v = *(const f32x4*)&I[(size_t)(rt + rr) * C + ct + c4];
    tile[rr][c4 + 0] = v[0]; tile[rr][c4 + 1] = v[1];
    tile[rr][c4 + 2] = v[2]; tile[rr][c4 + 3] = v[3];
  }
  __syncthreads();
  #pragma unroll
  for (int i = 0; i < 4; i++) {
    int oc = i * 16 + (t >> 4);
    f32x4 tv;
    #pragma unroll
    for (int rr = 0; rr < 4; rr++) tv[rr] = tile[c4 + rr][oc] * scale;
    *(u16x4*)&O[(size_t)(ct + oc) * R + rt + c4] = pk4(tv);
  }
}

#define STAGE_TILES() do { \
    GLL16(Ag + kt,             AsB0); \
    GLL16(Ag + 64 * 1024 + kt, AsB0 + 2048); \
    GLL16(Bg + kt,             BsB0); \
    GLL16(Bg + 64 * 1024 + kt, BsB0 + 2048); \
  } while (0)

#define READ_FRAGS() do { \
    _Pragma("unroll") \
    for (int mi = 0; mi < 4; mi++) \
      af[mi] = *(const u16x8*)&As[(wr * 64 + mi * 16 + lr) * 32 + lg * 8]; \
    _Pragma("unroll") \
    for (int ni = 0; ni < 4; ni++) \
      bf[ni] = *(const u16x8*)&Bs[(wc * 64 + ni * 16 + lr) * 32 + lg * 8]; \
  } while (0)

// ---- m97-structure GEMM: 128x128 tile, BK=32, 4 waves, global_load_lds staging ----
// merged QKV, grid (64,24). by 0..7 Q, 8..15 K (swapped mfma), 16..23 V (normal).
template<int MODE>
__global__ __launch_bounds__(256, 4) void k_gemm(
    const u16* __restrict__ X0, const u16* __restrict__ Ball,
    u16* __restrict__ O0, u16* __restrict__ O1, u16* __restrict__ O2) {
  const int bid = blockIdx.x + (blockIdx.y << 6);
  const int bx  = ((bid & 7) << 3) + ((bid >> 3) & 7);   // m-tile, XCD-local slice
  const int by  = bid >> 6;                               // n-tile
  const int l  = threadIdx.x & 63;
  const int w  = threadIdx.x >> 6;
  const int lr = l & 15, lg = l >> 4;
  const int wr = w >> 1, wc = w & 1;
  const int m0 = bx * 128;

  const u16* A = X0 + (size_t)(by >> 3) * (8 << 20);

  __shared__ __align__(16) u16 As[128 * 32];
  __shared__ __align__(16) u16 Bs[128 * 32];

  const int srow = w * 16 + (l >> 2);
  const int scol = (l & 3) * 8;
  const u16* Ag = A    + (size_t)(m0 + srow) * 1024 + scol;
  const u16* Bg = Ball + (size_t)(by * 128 + srow) * 1024 + scol;
  u16* AsB0 = As + w * 512;           // uniform per wave
  u16* BsB0 = Bs + w * 512;

  f32x4 acc[4][4] = {};
  u16x8 af[4], bf[4];

  if (by < 16) {
    for (int kt = 0; kt < 1024; kt += 32) {
      STAGE_TILES();
      __syncthreads();
      READ_FRAGS();
      #pragma unroll
      for (int mi = 0; mi < 4; mi++)
        #pragma unroll
        for (int ni = 0; ni < 4; ni++)
          acc[mi][ni] = MFMA16(bf[ni], af[mi], acc[mi][ni]);   // swapped
      __syncthreads();
    }
  } else {
    for (int kt = 0; kt < 1024; kt += 32) {
      STAGE_TILES();
      __syncthreads();
      READ_FRAGS();
      #pragma unroll
      for (int mi = 0; mi < 4; mi++)
        #pragma unroll
        for (int ni = 0; ni < 4; ni++)
          acc[mi][ni] = MFMA16(af[mi], bf[ni], acc[mi][ni]);   // normal (V)
      __syncthreads();
    }
  }

  if (by < 16) {
    u16* Out = (by >= 8) ? O1 : O0;
    const int h = (by & 7) * 2 + wc;
    #pragma unroll
    for (int mi = 0; mi < 4; mi++) {
      int s = m0 + wr * 64 + mi * 16 + lr;
      int bb = s >> 10, ss = s & 1023;
      #pragma unroll
      for (int ni = 0; ni < 4; ni++)
        *(u16x4*)&Out[((size_t)(h * 8 + bb) * 1024 + ss) * 64 + ni * 16 + lg * 4] =
            pk4(acc[mi][ni]);
    }
  } else {
    const int byv = by - 16;
    const int h = byv * 2 + wc;
    #pragma unroll
    for (int mi = 0; mi < 4; mi++) {
      int s = m0 + wr * 64 + mi * 16 + lg * 4;
      int bb = s >> 10, ss = s & 1023;
      #pragma unroll
      for (int ni = 0; ni < 4; ni++)
        *(u16x4*)&O2[((size_t)(h * 8 + bb) * 64 + ni * 16 + lr) * 1024 + ss] =
            pk4(acc[mi][ni]);
    }
  }
}

// ---- proj GEMM: BM=128 x BN=64, BK=32 -> grid 1024 wgs. Swapped mfma ->
// D[row=n][col=m]; epilogue fuses +bias+residual, stores P as BF16 (LN re-derives
// stats from rounded values -> self-consistent; saves 32MB of HBM round-trip).
__global__ __launch_bounds__(256, 4) void k_proj(const u16* __restrict__ AO,
    const u16* __restrict__ Wpt, const float* __restrict__ bp,
    const float* __restrict__ query, u16* __restrict__ Pb) {
  const int bid = blockIdx.x;
  const int bx  = ((bid & 7) << 3) + ((bid >> 3) & 7);   // 0..63, XCD-local slice
  const int by  = bid >> 6;                               // 0..15
  const int l  = threadIdx.x & 63;
  const int w  = threadIdx.x >> 6;
  const int lr = l & 15, lg = l >> 4;
  const int wr = w >> 1, wc = w & 1;
  const int m0 = bx * 128, n0 = by * 64;

  __shared__ __align__(16) u16 As[128 * 32];   // 8 KB
  __shared__ __align__(16) u16 Bs[64 * 32];    // 4 KB

  const int srow = w * 16 + (l >> 2);          // < 64
  const int scol = (l & 3) * 8;
  const u16* Ag = AO  + (size_t)(m0 + srow) * 1024 + scol;
  const u16* Bg = Wpt + (size_t)(n0 + srow) * 1024 + scol;
  u16* AsB0 = As + w * 512;
  u16* BsB0 = Bs + w * 512;

  f32x4 acc[4][2] = {};

  for (int kt = 0; kt < 1024; kt += 32) {
    GLL16(Ag + kt,             AsB0);
    GLL16(Ag + 64 * 1024 + kt, AsB0 + 2048);
    GLL16(Bg + kt,             BsB0);
    __syncthreads();

    u16x8 af[4], bf[2];
    #pragma unroll
    for (int mi = 0; mi < 4; mi++)
      af[mi] = *(const u16x8*)&As[(wr * 64 + mi * 16 + lr) * 32 + lg * 8];
    #pragma unroll
    for (int ni = 0; ni < 2; ni++)
      bf[ni] = *(const u16x8*)&Bs[(wc * 32 + ni * 16 + lr) * 32 + lg * 8];

    #pragma unroll
    for (int mi = 0; mi < 4; mi++)
      #pragma unroll
      for (int ni = 0; ni < 2; ni++)
        acc[mi][ni] = MFMA16(bf[ni], af[mi], acc[mi][ni]);  // D[row=n][col=m]
    __syncthreads();
  }

  #pragma unroll
  for (int mi = 0; mi < 4; mi++) {
    int m = m0 + wr * 64 + mi * 16 + lr;
    #pragma unroll
    for (int ni = 0; ni < 2; ni++) {
      int n = n0 + wc * 32 + ni * 16 + lg * 4;
      f32x4 b4 = *(const f32x4*)(bp + n);
      f32x4 q4 = *(const f32x4*)(query + (size_t)m * 1024 + n);
      f32x4 o = acc[mi][ni] + b4 + q4;
      *(u16x4*)&Pb[(size_t)m * 1024 + n] = pk4(o);
    }
  }
}

// ---- attention (R12-exact): wg = (hb, 16 q rows); ONE barrier. Post-barrier:
// issue slice0-tail + slice1 V loads -> 16 row-contiguous 1KB NT stores ->
// PV slice-by-slice with single accumulator + inter-slice rescale.
__global__ __launch_bounds__(256, 4) void k_attn(const u16* __restrict__ Qb,
    const u16* __restrict__ Kb, const u16* __restrict__ Vtb,
    float* __restrict__ attn_out, u16* __restrict__ AO) {
  const int bid = blockIdx.x;
  const int xcd = bid & 7, within = bid >> 3;
  const int qt = within & 63;
  const int hb = xcd * 16 + (within >> 6);
  const int w  = threadIdx.x >> 6;
  const int l  = threadIdx.x & 63;
  const int lr = l & 15, lg = l >> 4;
  const int q0 = qt * 16;

  __shared__ __align__(16) u16 pbuf[16 * 1024];   // 32 KB, swizzled; raw exp2(s - wmax_w)
  __shared__ float wmaxs[4][16];
  __shared__ float wsums[4][16];

  // --- QK^T swapped: mfma(K,Q) -> thread holds S[q=lr][k = w*256 + j*16 + lg*4 + r]
  const u16* Qp = Qb + ((size_t)hb * 1024 + q0 + lr) * 64 + lg * 8;
  const u16* Kp = Kb + ((size_t)hb * 1024 + w * 256 + lr) * 64 + lg * 8;
  u16x8 q_lo = *(const u16x8*)Qp;
  u16x8 q_hi = *(const u16x8*)(Qp + 32);

  f32x4 sacc[16] = {};
  __builtin_amdgcn_s_setprio(1);
  #pragma unroll
  for (int j = 0; j < 16; j++) {
    u16x8 k0 = *(const u16x8*)(Kp + (size_t)j * 16 * 64);
    u16x8 k1 = *(const u16x8*)(Kp + (size_t)j * 16 * 64 + 32);
    sacc[j] = MFMA16(k0, q_lo, sacc[j]);
    sacc[j] = MFMA16(k1, q_hi, sacc[j]);
  }
  __builtin_amdgcn_s_setprio(0);

  // --- wave-local row max over this wave's 256-col slice ---
  float mx = sacc[0][0];
  #pragma unroll
  for (int j = 0; j < 16; j++)
    #pragma unroll
    for (int r = 0; r < 4; r++) mx = fmaxf(mx, sacc[j][r]);
  mx = fmaxf(mx, __shfl_xor(mx, 16));
  mx = fmaxf(mx, __shfl_xor(mx, 32));

  // --- exp2(s - wmax) + wave-local sum (v_exp_f32 is 2^x; scores pre-scaled) ---
  float sum = 0.f;
  #pragma unroll
  for (int j = 0; j < 16; j++)
    #pragma unroll
    for (int r = 0; r < 4; r++) {
      float p = exp2_hw(sacc[j][r] - mx);
      sacc[j][r] = p;
      sum += p;
    }
  sum += __shfl_xor(sum, 16);
  sum += __shfl_xor(sum, 32);

  // --- prefetch V slice0 kk=0..3 (latency hides under LDS writes + barrier) ---
  const u16* Vp = Vtb + ((size_t)hb * 64 + w * 16 + lr) * 1024 + lg * 8;
  u16x8 vp0 = *(const u16x8*)(Vp + 0);
  u16x8 vp1 = *(const u16x8*)(Vp + 32);
  u16x8 vp2 = *(const u16x8*)(Vp + 64);
  u16x8 vp3 = *(const u16x8*)(Vp + 96);

  // --- raw-exp2 P -> swizzled pbuf (bf16); sacc DIES here ---
  #pragma unroll
  for (int j = 0; j < 16; j++) {
    int k0 = w * 256 + j * 16 + lg * 4;
    int byte = (lr * 2048 + k0 * 2) ^ ((lr & 7) << 4);
    *(u16x4*)((char*)pbuf + byte) = pk4(sacc[j]);
  }
  if (l < 16) { wmaxs[w][lr] = mx; wsums[w][lr] = sum; }

  __syncthreads();   // the only barrier: drains LDS writes only (no global stores yet)

  // --- combine for PV (row q = lr): rescale ratios + final coef ---
  float m0v = wmaxs[0][lr], m1v = wmaxs[1][lr], m2v = wmaxs[2][lr], m3v = wmaxs[3][lr];
  float gmax = fmaxf(fmaxf(m0v, m1v), fmaxf(m2v, m3v));
  float gsum = wsums[0][lr] * exp2_hw(m0v - gmax) + wsums[1][lr] * exp2_hw(m1v - gmax)
             + wsums[2][lr] * exp2_hw(m2v - gmax) + wsums[3][lr] * exp2_hw(m3v - gmax);
  float r01 = exp2_hw(m0v - m1v);
  float r12 = exp2_hw(m1v - m2v);
  float r23 = exp2_hw(m2v - m3v);
  float c3  = exp2_hw(m3v - gmax) / gsum;

  // --- issue slice0 tail + slice1 V loads BEFORE any store hits the queue ---
  u16x8 vp4 = *(const u16x8*)(Vp + 128);
  u16x8 vp5 = *(const u16x8*)(Vp + 160);
  u16x8 vp6 = *(const u16x8*)(Vp + 192);
  u16x8 vp7 = *(const u16x8*)(Vp + 224);
  u16x8 vq0 = *(const u16x8*)(Vp + 256);
  u16x8 vq1 = *(const u16x8*)(Vp + 288);
  u16x8 vq2 = *(const u16x8*)(Vp + 320);
  u16x8 vq3 = *(const u16x8*)(Vp + 352);
  u16x8 vq4 = *(const u16x8*)(Vp + 384);
  u16x8 vq5 = *(const u16x8*)(Vp + 416);
  u16x8 vq6 = *(const u16x8*)(Vp + 448);
  u16x8 vq7 = *(const u16x8*)(Vp + 480);

  // --- attn f32 out: wave w owns rows [w*4, w*4+4); per (row, chunk) scale is
  //     lane-uniform -> one contiguous 1KB NT store per instruction ---
  #pragma unroll
  for (int rr = 0; rr < 4; rr++) {
    const int row = w * 4 + rr;
    float M0 = wmaxs[0][row], M1 = wmaxs[1][row], M2 = wmaxs[2][row], M3 = wmaxs[3][row];
    float GM = fmaxf(fmaxf(M0, M1), fmaxf(M2, M3));
    float E0 = exp2_hw(M0 - GM), E1 = exp2_hw(M1 - GM);
    float E2 = exp2_hw(M2 - GM), E3 = exp2_hw(M3 - GM);
    float IV = 1.0f / (wsums[0][row] * E0 + wsums[1][row] * E1 +
                       wsums[2][row] * E2 + wsums[3][row] * E3);
    float cs0 = E0 * IV, cs1 = E1 * IV, cs2 = E2 * IV, cs3 = E3 * IV;
    float* Ap = attn_out + ((size_t)hb * 1024 + q0 + row) * 1024;
    #pragma unroll
    for (int c = 0; c < 4; c++) {
      float sc = c == 0 ? cs0 : c == 1 ? cs1 : c == 2 ? cs2 : cs3;
      int byte = (row * 2048 + (c * 256 + l * 4) * 2) ^ ((row & 7) << 4);
      u32x2 d = *(u32x2*)((char*)pbuf + byte);
      f32x4 v;
      v[0] = bflo(d[0]) * sc;
      v[1] = bfhi(d[0]) * sc;
      v[2] = bflo(d[1]) * sc;
      v[3] = bfhi(d[1]) * sc;
      __builtin_nontemporal_store(v, (f32x4*)(Ap + c * 256 + l * 4));
    }
  }

  // --- PV: mfma(V, P) -> D[row=e][col=q=lr]; single acc + inter-slice rescale ---
  f32x4 o = {};
  __builtin_amdgcn_s_setprio(1);
  #define PBUF_P(i, kk) (*(u16x8*)((char*)pbuf + \
      ((lr * 2048 + ((i) * 256 + (kk) * 32 + lg * 8) * 2) ^ ((lr & 7) << 4))))
  // slice 0 (registers loaded pre-barrier / pre-store)
  o = MFMA16(vp0, PBUF_P(0, 0), o);
  o = MFMA16(vp1, PBUF_P(0, 1), o);
  o = MFMA16(vp2, PBUF_P(0, 2), o);
  o = MFMA16(vp3, PBUF_P(0, 3), o);
  o = MFMA16(vp4, PBUF_P(0, 4), o);
  o = MFMA16(vp5, PBUF_P(0, 5), o);
  o = MFMA16(vp6, PBUF_P(0, 6), o);
  o = MFMA16(vp7, PBUF_P(0, 7), o);
  // issue slice2 loads (reuse vp regs; store queue partially drained by now)
  vp0 = *(const u16x8*)(Vp + 512);
  vp1 = *(const u16x8*)(Vp + 544);
  vp2 = *(const u16x8*)(Vp + 576);
  vp3 = *(const u16x8*)(Vp + 608);
  vp4 = *(const u16x8*)(Vp + 640);
  vp5 = *(const u16x8*)(Vp + 672);
  vp6 = *(const u16x8*)(Vp + 704);
  vp7 = *(const u16x8*)(Vp + 736);
  o *= r01;
  // slice 1 (loaded before stores)
  o = MFMA16(vq0, PBUF_P(1, 0), o);
  o = MFMA16(vq1, PBUF_P(1, 1), o);
  o = MFMA16(vq2, PBUF_P(1, 2), o);
  o = MFMA16(vq3, PBUF_P(1, 3), o);
  o = MFMA16(vq4, PBUF_P(1, 4), o);
  o = MFMA16(vq5, PBUF_P(1, 5), o);
  o = MFMA16(vq6, PBUF_P(1, 6), o);
  o = MFMA16(vq7, PBUF_P(1, 7), o);
  // issue slice3 loads
  vq0 = *(const u16x8*)(Vp + 768);
  vq1 = *(const u16x8*)(Vp + 800);
  vq2 = *(const u16x8*)(Vp + 832);
  vq3 = *(const u16x8*)(Vp + 864);
  vq4 = *(const u16x8*)(Vp + 896);
  vq5 = *(const u16x8*)(Vp + 928);
  vq6 = *(const u16x8*)(Vp + 960);
  vq7 = *(const u16x8*)(Vp + 992);
  o *= r12;
  // slice 2
  o = MFMA16(vp0, PBUF_P(2, 0), o);
  o = MFMA16(vp1, PBUF_P(2, 1), o);
  o = MFMA16(vp2, PBUF_P(2, 2), o);
  o = MFMA16(vp3, PBUF_P(2, 3), o);
  o = MFMA16(vp4, PBUF_P(2, 4), o);
  o = MFMA16(vp5, PBUF_P(2, 5), o);
  o = MFMA16(vp6, PBUF_P(2, 6), o);
  o = MFMA16(vp7, PBUF_P(2, 7), o);
  o *= r23;
  // slice 3
  o = MFMA16(vq0, PBUF_P(3, 0), o);
  o = MFMA16(vq1, PBUF_P(3, 1), o);
  o = MFMA16(vq2, PBUF_P(3, 2), o);
  o = MFMA16(vq3, PBUF_P(3, 3), o);
  o = MFMA16(vq4, PBUF_P(3, 4), o);
  o = MFMA16(vq5, PBUF_P(3, 5), o);
  o = MFMA16(vq6, PBUF_P(3, 6), o);
  o = MFMA16(vq7, PBUF_P(3, 7), o);
  __builtin_amdgcn_s_setprio(0);
  #undef PBUF_P

  // --- AO store: q = lr, e = w*16 + lg*4 + r -> one u16x4 ---
  const int bb = hb & 7, hh = hb >> 3;
  f32x4 oc = o * c3;
  *(u16x4*)&AO[((size_t)bb * 1024 + q0 + lr) * 1024 + hh * 64 + w * 16 + lg * 4] = pk4(oc);
}

// ---- standalone LayerNorm over bf16 P rows (bias+residual already in P) ----
__global__ __launch_bounds__(256) void k_ln(const u16* __restrict__ Pb,
    const float* __restrict__ gamma, const float* __restrict__ beta,
    float* __restrict__ y) {
  const int row = blockIdx.x * 4 + (threadIdx.x >> 6);
  const int l = threadIdx.x & 63;
  const u16* p = Pb + (size_t)row * 1024 + l * 8;
  float v[16];
  float s = 0.f, s2 = 0.f;
  #pragma unroll
  for (int i = 0; i < 2; i++) {
    u32x4 d = *(const u32x4*)(p + i * 512);
    #pragma unroll
    for (int j = 0; j < 4; j++) {
      float lo = bflo(d[j]), hi = bfhi(d[j]);
      v[i * 8 + j * 2 + 0] = lo;
      v[i * 8 + j * 2 + 1] = hi;
      s += lo + hi;
      s2 += lo * lo + hi * hi;
    }
  }
  #pragma unroll
  for (int off = 1; off < 64; off <<= 1) {
    s += __shfl_xor(s, off);
    s2 += __shfl_xor(s2, off);
  }
  float mu = s * (1.0f / 1024.0f);
  float var = s2 * (1.0f / 1024.0f) - mu * mu;
  float rstd = rsqrtf(var + LN_EPS);
  float* yp = y + (size_t)row * 1024 + l * 8;
  #pragma unroll
  for (int i = 0; i < 2; i++) {
    f32x4 o0, o1;
    #pragma unroll
    for (int j = 0; j < 4; j++) {
      int idx = i * 8 + j * 2;
      float g0 = gamma[l * 8 + i * 512 + j * 2], g1 = gamma[l * 8 + i * 512 + j * 2 + 1];
      float b0 = beta[l * 8 + i * 512 + j * 2],  b1 = beta[l * 8 + i * 512 + j * 2 + 1];
      float r0 = (v[idx] - mu) * rstd * g0 + b0;
      float r1 = (v[idx + 1] - mu) * rstd * g1 + b1;
      if (j < 2) { o0[j * 2] = r0; o0[j * 2 + 1] = r1; }
      else { o1[(j - 2) * 2] = r0; o1[(j - 2) * 2 + 1] = r1; }
    }
    __builtin_nontemporal_store(o0, (f32x4*)(yp + i * 512));
    __builtin_nontemporal_store(o1, (f32x4*)(yp + i * 512 + 4));
  }
}

extern "C" void kernel_launch(void* const* d_in, const int* in_sizes, int n_in,
                              void* d_out, int out_size, void* d_ws, size_t ws_size,
                              hipStream_t stream) {
  const float* query  = (const float*)d_in[0];
  const float* keys   = (const float*)d_in[1];
  const float* values = (const float*)d_in[2];
  const float* Wq     = (const float*)d_in[3];
  const float* Wk     = (const float*)d_in[4];
  const float* Wv     = (const float*)d_in[5];
  const float* Wp     = (const float*)d_in[6];
  const float* bp     = (const float*)d_in[7];
  const float* gamma  = (const float*)d_in[8];
  const float* beta   = (const float*)d_in[9];

  float* y        = (float*)d_out;                         // [8,1024,1024]
  float* attn_out = (float*)d_out + (size_t)B_ * S_ * D_;  // [128,1024,1024]

  u16* ws  = (u16*)d_ws;
  u16* Wqt = ws;                   // weights: Wq|Wk|Wv|Wp transposed, 4M u16
  u16* Wpt = Wqt + (3 << 20);
  u16* Xqb = Wqt + (4 << 20);      // Xq|Xk|Xv bf16, 24M u16
  u16* Qb  = Xqb + (24 << 20);     // 8M each
  u16* Kb  = Qb + (8 << 20);
  u16* Vtb = Kb + (8 << 20);
  u16* AO  = Vtb + (8 << 20);      // 8M
  u16* Pb  = (u16*)Xqb;            // proj+residual bf16 (8M), overlays Xqb (dead by then)

  k_prep<<<13312, 256, 0, stream>>>(Wq, Wk, Wv, Wp, Wqt, query, keys, values, Xqb);

  // merged QKV GEMM: by 0..7 Q, 8..15 K, 16..23 V
  k_gemm<0><<<dim3(64, 24), 256, 0, stream>>>(Xqb, Wqt, Qb, Kb, Vtb);

  k_attn<<<8192, 256, 0, stream>>>(Qb, Kb, Vtb, attn_out, AO);

  k_proj<<<1024, 256, 0, stream>>>(AO, Wpt, bp, query, Pb);
  k_ln<<<2048, 256, 0, stream>>>(Pb, gamma, beta, y);
}